// Round 10
// baseline (294.063 us; speedup 1.0000x reference)
//
#include <hip/hip_runtime.h>
#include <cstdint>
#include <cstddef>

// ---------- fp16/bf16 helpers ----------
typedef __attribute__((ext_vector_type(8))) _Float16 half8;
typedef __attribute__((ext_vector_type(8))) short short8;
typedef __attribute__((ext_vector_type(4))) float floatx4;

static __device__ __forceinline__ uint16_t f2h(float f) {
    _Float16 h = (_Float16)f;
    uint16_t u;
    __builtin_memcpy(&u, &h, 2);
    return u;
}
static __device__ __forceinline__ float h2f(uint16_t u) {
    _Float16 h;
    __builtin_memcpy(&h, &u, 2);
    return (float)h;
}
static __device__ __forceinline__ uint16_t f2bf(float f) {
    uint32_t u;
    __builtin_memcpy(&u, &f, 4);
    u += 0x7fffu + ((u >> 16) & 1u);  // round-to-nearest-even
    return (uint16_t)(u >> 16);
}
// packed f32x2 -> bf16x2 (RNE), one instruction (HW-verified r9: %1 -> low 16, %2 -> high)
static __device__ __forceinline__ uint32_t cvt_pk_bf16(float lo, float hi) {
    uint32_t r;
    asm("v_cvt_pk_bf16_f32 %0, %1, %2" : "=v"(r) : "v"(lo), "v"(hi));
    return r;
}
// packed f32x2 -> f16x2 (RTZ), one instruction; <=1 ulp fp16 vs RNE.
// builtin returns __fp16 ext_vector(2) — take as auto, memcpy the bits (r8 fix).
static __device__ __forceinline__ uint32_t pkh(float lo, float hi) {
    auto h = __builtin_amdgcn_cvt_pkrtz(lo, hi);
    uint32_t u;
    __builtin_memcpy(&u, &h, 4);
    return u;
}
// D = 2^S0 (ISA §3 v_exp_f32); pure VALU, register-dep interlocked in HW
static __device__ __forceinline__ float exp2v(float x) {
    float r;
    asm("v_exp_f32 %0, %1" : "=v"(r) : "v"(x));
    return r;
}

// async global->LDS, 16B per lane (dest = wave-uniform base + lane*16 — our chunk layout).
static __device__ __forceinline__ void g2lds16(const void* g, void* l) {
    __builtin_amdgcn_global_load_lds((__attribute__((address_space(1))) void*)g,
                                     (__attribute__((address_space(3))) void*)l, 16, 0, 0);
}

#define LOG2E 1.44269504088896340f

// ---------- weights fp32->fp16 (+ zero the L accumulator), one launch ----------
// Wm: ic-columns perm64'd (chain-3, HW-verified r5).
// w_theta: pre-scaled by log2e (scores epilogue uses raw v_exp_f32; HW-verified r9).
__global__ void cvt_weights(const float* __restrict__ wphi, const float* __restrict__ wtheta,
                            const float* __restrict__ wg, const float* __restrict__ wmask,
                            uint16_t* __restrict__ W3, uint16_t* __restrict__ Wm, float* __restrict__ L) {
    int seg = blockIdx.y;
    int i = blockIdx.x * 256 + threadIdx.x;
    if (seg == 4) {
        if (i < 16384) L[i] = 0.f;
        return;
    }
    int base = i * 4;  // grid.x=128 -> base < 131072 exactly
    if (seg == 3) {
        // stored cols base..base+3 = row*256 + blk + 4a + {0..3}  <-  natural cols blk + a + 16i
        int row = base >> 8, dc = base & 255;
        int blk = dc & 192, a = (dc >> 2) & 15;
        const float* s = wmask + row * 256 + blk + a;
        *(ushort4*)(Wm + base) = make_ushort4(f2h(s[0]), f2h(s[16]), f2h(s[32]), f2h(s[48]));
        return;
    }
    const float* src = seg == 0 ? wphi : seg == 1 ? wtheta : wg;
    float4 v = *(const float4*)(src + base);
    float sc = (seg == 1) ? LOG2E : 1.f;
    *(ushort4*)(W3 + seg * 131072 + base) =
        make_ushort4(f2h(v.x * sc), f2h(v.y * sc), f2h(v.z * sc), f2h(v.w * sc));
}

// ---------- transpose x: (b,512,4096) f32 -> Xt (b,4096,512) f16 ----------
__global__ __launch_bounds__(256) void transpose_x(const float* __restrict__ x, uint16_t* __restrict__ xt) {
    __shared__ uint16_t tile[64][66];
    int b = blockIdx.z, p0 = blockIdx.x * 64, c0 = blockIdx.y * 64;
    int t0 = threadIdx.x & 63, t1 = threadIdx.x >> 6;
    const float* xb = x + ((long)b * 512 + c0) * 4096 + p0;
#pragma unroll
    for (int r = 0; r < 16; ++r) {
        int cc = t1 * 16 + r;
        tile[cc][t0] = f2h(xb[(long)cc * 4096 + t0]);
    }
    __syncthreads();
    uint16_t* xtb = xt + ((long)b * 4096 + p0) * 512 + c0;
#pragma unroll
    for (int r = 0; r < 16; ++r) {
        int pp = t1 * 16 + r;
        xtb[(long)pp * 512 + t0] = tile[t0][pp];
    }
}

// ---------- scale+normalize g: Gc (fp16) -> Gc (bf16), element f *= 1/L[f & 2047] ----------
// Operates on STORED labels (chain-2): producers wrote Gc cols and L at the same relabel.
__global__ void scale_g(uint16_t* __restrict__ gc, const float* __restrict__ L) {
    long t = (long)blockIdx.x * 256 + threadIdx.x;  // 1,048,576 threads, 8 elems each
    long base = t * 8;
    int j0 = (int)(base & 2047);
    int b = (int)(base >> 20);  // 256*4096 elems per batch
    const float* Lp = L + (long)b * 2048 + j0;
    float4 l0 = *(const float4*)Lp;
    float4 l1 = *(const float4*)(Lp + 4);
    float rr[8] = {1.f / l0.x, 1.f / l0.y, 1.f / l0.z, 1.f / l0.w, 1.f / l1.x, 1.f / l1.y, 1.f / l1.z, 1.f / l1.w};
    uint4 v = *(uint4*)(gc + base);
    uint32_t* pv = (uint32_t*)&v;
    uint32_t o[4];
#pragma unroll
    for (int e = 0; e < 4; ++e) {
        float a = h2f((uint16_t)(pv[e] & 0xffffu)) * rr[2 * e];
        float c = h2f((uint16_t)(pv[e] >> 16)) * rr[2 * e + 1];
        o[e] = (uint32_t)f2bf(a) | ((uint32_t)f2bf(c) << 16);
    }
    *(uint4*)(gc + base) = *(uint4*)o;
}

// ---------- NT GEMM: C[m][n] = sum_k A[m][k]*B[n][k] ----------
// 128x128 tile, BK=64 staged as TWO stacked [128][32] LDS panels; nK = K/64.
// 4 waves each 64x64 (4x4 of 16x16x32 MFMA, 2 k-steps per iter).
// KHALF: for k>=256 both A and B row bases shift by 2048 rows, k -= 256 (channel-view split).
//
// Label relabels (perm64(l)=(l&15)*4+(l>>4) within 64-blocks):
//  chain-1 (this round): C2 channel cols perm64'd. Safe because BOTH scores operands read
//  C2 linearly (A stored cols [256,512), B stored cols [0,256)): stored offset t maps to
//  natural channel invp64(t) on both sides (256 is 64-block-aligned), so the dot-product
//  pairing is preserved and the k-sum is label-invariant. KHALF's pixel-half row shift is
//  orthogonal to the col perm. No other consumer reads C2 (Y2 only reuses the dead buffer).
//  chain-2 (HW-verified r4): attention j-label shared by {P cols, L index, Gc pixel cols}.
//  chain-3 (HW-verified r5): Y2 de-interleaved+perm64'd via BMODE=3, matching perm'd Wm.
//
// XSWZ (HW-verified r7: scores FETCH 73.8->28.4 MB): 1D grid, wgid&7 = batch -> one batch
// per XCD (C2 4MB = L2/XCD); rest>>=3 decoded bx-fastest. gxs = log2(grid-x count).
//
// EPI: 0 = fp16 C, pkrtz-packed ushort4 over nt at perm64'd cols (PV -> Y2);
//      1 = fp32 C[m][n] + residual (final output, natural, scatter);
//      3 = mixed conv epilogue: n0<512 -> C2 packed ushort4 at perm64'd cols (chain-1;
//          f2h RNE so C2 VALUES are unchanged — only store addresses permute);
//          n0>=512 -> transposed Gc[n-512][m], PIXEL cols perm64'd, pkrtz-packed over mt;
//      4 = bf16 P[m][n'] = 2^acc via v_exp_f32 + v_cvt_pk_bf16_f32, packed uint2 at
//          perm64'd cols; column sums shfl-transposed -> ONE lane-contiguous atomic/wave.
// SWAP: m0 from by, n0 from bx (consecutive blocks share the A-tile)
// BMODE: 0 = plain row*ldb async staging;
//        2 = mask B from de-interleaved Y2: row p -> (p&2047)*ldb + 256*(p>>11) (async);
//        3 = PV B de-interleave: logical col n reads Gc flat (n&255)*4096 + (n>>8)*2048 + k.
// DT: 0 = fp16 MFMA, 1 = bf16 MFMA (fragment/CD layouts are dtype-independent)
template <bool KHALF, int EPI, bool SWAP, int BMODE, int DT, bool XSWZ>
__global__ __launch_bounds__(256) void gemm_nt(const uint16_t* __restrict__ A, const uint16_t* __restrict__ B,
                                               void* __restrict__ Cout, const float* __restrict__ resid,
                                               int lda, int ldb, int ldc, int nK,
                                               long aBatch, long bBatch, long cBatch,
                                               void* __restrict__ Cout2, int ldc2, long c2Batch,
                                               float* __restrict__ Lsum, int gxs) {
    __shared__ uint16_t Al[2 * 128 * 32];
    __shared__ uint16_t Bl[2 * 128 * 32];
    int bx, by, b;
    if (XSWZ) {
        int wg = blockIdx.x;
        b = wg & 7;
        int rest = wg >> 3;
        bx = rest & ((1 << gxs) - 1);
        by = rest >> gxs;
    } else {
        bx = blockIdx.x; by = blockIdx.y; b = blockIdx.z;
    }
    const uint16_t* Ab = A + (long)b * aBatch;
    const uint16_t* Bb = B + (long)b * bBatch;
    const int m0 = (SWAP ? by : bx) * 128;
    const int n0 = (SWAP ? bx : by) * 128;
    const int tid = threadIdx.x;
    const int lane = tid & 63, wave = tid >> 6;
    const int ln = lane & 15, q = lane >> 4;
    const int wm = (wave & 1) * 64, wn = (wave >> 1) * 64;

    // softmax shift folded into the accumulator: acc holds S*log2e - 12*log2e (theta
    // pre-scaled by log2e at cvt time), so P = 2^acc directly.
    const float ainit = (EPI == 4) ? (-12.f * LOG2E) : 0.f;
    floatx4 acc[4][4];
#pragma unroll
    for (int i = 0; i < 4; ++i)
#pragma unroll
        for (int j = 0; j < 4; ++j) acc[i][j] = (floatx4){ainit, ainit, ainit, ainit};

    for (int kt = 0; kt < nK; ++kt) {
        int k0 = kt * 64;
#pragma unroll
        for (int half = 0; half < 2; ++half) {
            int kh = k0 + half * 32;
            int keff = kh;
            long roff = 0;
            if (KHALF && kh >= 256) { keff = kh - 256; roff = 2048; }
            uint16_t* AlH = &Al[half * 4096];
            uint16_t* BlH = &Bl[half * 4096];
#pragma unroll
            for (int s = 0; s < 2; ++s) {
                int c = tid + s * 256;  // 512 chunks of 16B per operand-panel
                int row = c >> 2, kq = (c & 3) * 8;
                g2lds16(Ab + ((long)(m0 + row) + roff) * lda + keff + kq, &AlH[c * 8]);
                if (BMODE == 0) {
                    g2lds16(Bb + ((long)(n0 + row) + roff) * ldb + keff + kq, &BlH[c * 8]);
                } else if (BMODE == 2) {
                    // mask B from de-interleaved Y2: pixel p -> stored row p&2047, +256 col
                    // offset for the upper pixel-half
                    int pg = n0 + row;
                    g2lds16(Bb + (long)(pg & 2047) * ldb + ((pg >> 11) << 8) + keff + kq, &BlH[c * 8]);
                } else {
                    // BMODE==3: logical col n -> Gc flat (n&255)*4096 + (n>>8)*2048 + k
                    int pr = n0 + row;
                    g2lds16(Bb + (long)(pr & 255) * 4096 + ((pr >> 8) << 11) + keff + kq, &BlH[c * 8]);
                }
            }
        }
        __syncthreads();
#pragma unroll
        for (int half = 0; half < 2; ++half) {
            const uint16_t* AlH = &Al[half * 4096];
            const uint16_t* BlH = &Bl[half * 4096];
            short8 af[4], bfr[4];
#pragma unroll
            for (int mt = 0; mt < 4; ++mt) af[mt] = *(const short8*)&AlH[(wm + mt * 16 + ln) * 32 + q * 8];
#pragma unroll
            for (int nt = 0; nt < 4; ++nt) bfr[nt] = *(const short8*)&BlH[(wn + nt * 16 + ln) * 32 + q * 8];
#pragma unroll
            for (int mt = 0; mt < 4; ++mt)
#pragma unroll
                for (int nt = 0; nt < 4; ++nt) {
                    if constexpr (DT == 0) {
                        half8 ah, bh;
                        __builtin_memcpy(&ah, &af[mt], 16);
                        __builtin_memcpy(&bh, &bfr[nt], 16);
                        acc[mt][nt] = __builtin_amdgcn_mfma_f32_16x16x32_f16(ah, bh, acc[mt][nt], 0, 0, 0);
                    } else {
                        acc[mt][nt] = __builtin_amdgcn_mfma_f32_16x16x32_bf16(af[mt], bfr[nt], acc[mt][nt], 0, 0, 0);
                    }
                }
        }
        __syncthreads();
    }

    // C/D layout (verified m89): col = lane&15, row = (lane>>4)*4 + reg
    // perm64 store identity: original col l = nt*16+ln -> stored col ln*4+nt (contig over nt)
    if (EPI == 0) {
        // PV -> Y2: pkrtz-packed ushort4 at perm64'd cols (chain-3)
        uint16_t* C = (uint16_t*)Cout + (long)b * cBatch;
        const int cb = n0 + wn + (ln << 2);
#pragma unroll
        for (int mt = 0; mt < 4; ++mt)
#pragma unroll
            for (int r = 0; r < 4; ++r) {
                int gm = m0 + wm + mt * 16 + q * 4 + r;
                uint2 u;
                u.x = pkh(acc[mt][0][r], acc[mt][1][r]);
                u.y = pkh(acc[mt][2][r], acc[mt][3][r]);
                *(uint2*)&C[(long)gm * ldc + cb] = u;
            }
    } else if (EPI == 3 && n0 < 512) {
        // C2: packed ushort4 at perm64'd channel cols (chain-1); f2h RNE keeps values
        // bit-identical to the scatter path — only the store addresses permute.
        uint16_t* C = (uint16_t*)Cout + (long)b * cBatch;
        const int cb = n0 + wn + (ln << 2);
#pragma unroll
        for (int mt = 0; mt < 4; ++mt)
#pragma unroll
            for (int r = 0; r < 4; ++r) {
                int gm = m0 + wm + mt * 16 + q * 4 + r;
                ushort4 u = make_ushort4(f2h(acc[mt][0][r]), f2h(acc[mt][1][r]),
                                         f2h(acc[mt][2][r]), f2h(acc[mt][3][r]));
                *(ushort4*)&C[(long)gm * ldc + cb] = u;
            }
    } else if (EPI == 4) {
        // P = 2^acc stored bf16 via v_exp_f32 + v_cvt_pk_bf16_f32, packed uint2 at
        // perm64'd cols; L accumulated from the exact fp32 values at the stored labels.
        uint16_t* C = (uint16_t*)Cout + (long)b * cBatch;
        const int cb = n0 + wn + (ln << 2);
        float cs[4] = {0.f, 0.f, 0.f, 0.f};
#pragma unroll
        for (int mt = 0; mt < 4; ++mt)
#pragma unroll
            for (int r = 0; r < 4; ++r) {
                int gm = m0 + wm + mt * 16 + q * 4 + r;
                float e0 = exp2v(acc[mt][0][r]);
                float e1 = exp2v(acc[mt][1][r]);
                float e2 = exp2v(acc[mt][2][r]);
                float e3 = exp2v(acc[mt][3][r]);
                cs[0] += e0; cs[1] += e1; cs[2] += e2; cs[3] += e3;
                uint2 wv;
                wv.x = cvt_pk_bf16(e0, e1);
                wv.y = cvt_pk_bf16(e2, e3);
                *(uint2*)&C[(long)gm * ldc + cb] = wv;
            }
        // q-fold: every lane then holds the full 64-row column sums for stored cols ln*4+nt
        cs[0] += __shfl_xor(cs[0], 16); cs[0] += __shfl_xor(cs[0], 32);
        cs[1] += __shfl_xor(cs[1], 16); cs[1] += __shfl_xor(cs[1], 32);
        cs[2] += __shfl_xor(cs[2], 16); cs[2] += __shfl_xor(cs[2], 32);
        cs[3] += __shfl_xor(cs[3], 16); cs[3] += __shfl_xor(cs[3], 32);
        // shfl-transpose: lane l takes cs[l&3] from lane (l>>2) -> ONE lane-contiguous
        // atomic per wave (64 consecutive floats, 4 cachelines; r4-verified)
        {
            int srcl = lane >> 2;
            float t0 = __shfl(cs[0], srcl);
            float t1 = __shfl(cs[1], srcl);
            float t2 = __shfl(cs[2], srcl);
            float t3 = __shfl(cs[3], srcl);
            int sel = lane & 3;
            float val = sel == 0 ? t0 : sel == 1 ? t1 : sel == 2 ? t2 : t3;
            atomicAdd(&Lsum[(long)b * 2048 + n0 + wn + lane], val);
        }
    } else if (EPI == 1) {
        float* C = (float*)Cout + (long)b * cBatch;
        const float* X = resid + (long)b * cBatch;
#pragma unroll
        for (int mt = 0; mt < 4; ++mt)
#pragma unroll
            for (int r = 0; r < 4; ++r) {
                int gm = m0 + wm + mt * 16 + q * 4 + r;
#pragma unroll
                for (int nt = 0; nt < 4; ++nt) {
                    int gn = n0 + wn + nt * 16 + ln;
                    long idx = (long)gm * ldc + gn;
                    C[idx] = acc[mt][nt][r] + X[idx];
                }
            }
    } else {
        // transposed epilogue into Cout2: row = gn - 512; pixel cols perm64'd (chain-2):
        // original pixel l = mt*16 + q*4 + r -> stored col q*16 + r*4 + mt (contig over mt)
        uint16_t* C = (uint16_t*)Cout2 + (long)b * c2Batch;
        const int cb = m0 + wm + q * 16;
#pragma unroll
        for (int nt = 0; nt < 4; ++nt) {
            int gn2 = n0 - 512 + wn + nt * 16 + ln;
            uint16_t* rowp = C + (long)gn2 * ldc2 + cb;
#pragma unroll
            for (int r = 0; r < 4; ++r) {
                uint2 u;
                u.x = pkh(acc[0][nt][r], acc[1][nt][r]);
                u.y = pkh(acc[2][nt][r], acc[3][nt][r]);
                *(uint2*)&rowp[r * 4] = u;
            }
        }
    }
}

// ---------- launch ----------
// ws layout:
//   W3 @ 0 (768x512 f16: phi|theta(x log2e)|g) ; Wm @ 786432 (512x256 f16, perm64 cols)
//   L  @ 1048576 (8x2048 f32)
//   A_region @ 1179648  (64 MB): Xt (32 MB) -> P (64 MB bf16)
//   B_region @ 68288512 (48 MB): C2 (32 MB) -> Y2 (16 MB) @ +0 ; Gc (16 MB) @ +32MB
// chain-1 (this round): C2 channel cols perm64'd; both scores operands consume the same
//   stored labels -> k-sum invariant (derivation at the kernel).
// chain-2 (HW-verified r4): j-label perm64 shared by {P cols, L index, Gc pixel cols}.
// chain-3 (HW-verified r5): PV BMODE=3 + EPI=0 perm64 store lands Y2 de-interleaved+
//   perm64'd, matching perm'd Wm + mask BMODE=2 async staging.
// XSWZ (HW-verified r7): 1D grids, wgid&7 = batch -> one batch per XCD.
extern "C" void kernel_launch(void* const* d_in, const int* in_sizes, int n_in, void* d_out, int out_size, void* d_ws,
                              size_t ws_size, hipStream_t stream) {
    const float* x = (const float*)d_in[0];
    const float* wphi = (const float*)d_in[1];
    const float* wtheta = (const float*)d_in[2];
    const float* wg = (const float*)d_in[3];
    const float* wmask = (const float*)d_in[4];
    float* out = (float*)d_out;
    char* ws = (char*)d_ws;

    uint16_t* W3 = (uint16_t*)(ws + 0);
    uint16_t* Wm = (uint16_t*)(ws + 786432);
    float* L = (float*)(ws + 1048576);
    char* A_region = ws + 1179648;
    char* B_region = ws + 68288512;
    uint16_t* Xt = (uint16_t*)A_region;
    uint16_t* P = (uint16_t*)A_region;
    uint16_t* C2 = (uint16_t*)B_region;
    uint16_t* Y2 = (uint16_t*)B_region;
    uint16_t* Gc = (uint16_t*)(B_region + 33554432);

    // weights -> fp16 (Wm perm64'd, theta x log2e), L zeroed (one launch)
    cvt_weights<<<dim3(128, 5), 256, 0, stream>>>(wphi, wtheta, wg, wmask, W3, Wm, L);

    // x -> Xt (pixel-major fp16)
    transpose_x<<<dim3(64, 8, 8), 256, 0, stream>>>(x, Xt);

    // fused 3-conv: 1536 = 8 batches x (32 m x 6 n), gxs=5. n0<512 -> C2 packed at
    // perm64'd channel cols (chain-1), n0>=512 -> Gc transposed, perm64'd pixel cols
    // (chain-2).
    gemm_nt<false, 3, false, 0, 0, true><<<dim3(1536), 256, 0, stream>>>(
        Xt, W3, C2, nullptr, 512, 512, 512, 8, 4096L * 512, 0, 4096L * 512, Gc, 4096, 256L * 4096, nullptr, 5);

    // scores (k-half row shift): 2048 = 8 x (16 m x 16 n), gxs=4. P[i][j'] = bf16(2^acc)
    // packed, L[j'] += 2^acc via per-wave lane-contiguous atomics; overwrites Xt (dead).
    // Reads C2 linearly on both operands -> chain-1 transparent here.
    gemm_nt<true, 4, false, 0, 0, true><<<dim3(2048), 256, 0, stream>>>(
        C2 + 256, C2, P, nullptr, 512, 512, 2048, 8, 4096L * 512, 4096L * 512, 2048L * 2048, nullptr, 0, 0, L, 4);

    // Gc[c][j'] *= 1/L[j'], fp16 -> bf16 in place (stored labels on both sides)
    scale_g<<<4096, 256, 0, stream>>>(Gc, L);

    // PV (bf16, all-async): 512 = 8 x (4 n x 16 m), gxs=2 with SWAP. BMODE=3 de-interleave
    // staging lands Y2 de-interleaved+perm64'd; EPI=0 pkrtz-packs. Y2 reuses C2 (dead).
    gemm_nt<false, 0, true, 3, 1, true><<<dim3(512), 256, 0, stream>>>(
        P, Gc, Y2, nullptr, 2048, 2048, 512, 32, 2048L * 2048, 1048576L, 2048L * 512, nullptr, 0, 0, nullptr, 2);

    // mask conv + residual: 1024 = 8 x (4 m x 32 n), gxs=2. B staged ASYNC from
    // de-interleaved Y2 (BMODE=2), Wm perm64'd.
    gemm_nt<false, 1, false, 2, 0, true><<<dim3(1024), 256, 0, stream>>>(
        Wm, Y2, out, x, 256, 512, 4096, 4, 0, 1048576L, 512L * 4096, nullptr, 0, 0, nullptr, 2);
}

// Round 11
// 279.325 us; speedup vs baseline: 1.0528x; 1.0528x over previous
//
#include <hip/hip_runtime.h>
#include <cstdint>
#include <cstddef>

// ---------- fp16/bf16 helpers ----------
typedef __attribute__((ext_vector_type(8))) _Float16 half8;
typedef __attribute__((ext_vector_type(8))) short short8;
typedef __attribute__((ext_vector_type(4))) float floatx4;

static __device__ __forceinline__ uint16_t f2h(float f) {
    _Float16 h = (_Float16)f;
    uint16_t u;
    __builtin_memcpy(&u, &h, 2);
    return u;
}
static __device__ __forceinline__ float h2f(uint16_t u) {
    _Float16 h;
    __builtin_memcpy(&h, &u, 2);
    return (float)h;
}
static __device__ __forceinline__ uint16_t f2bf(float f) {
    uint32_t u;
    __builtin_memcpy(&u, &f, 4);
    u += 0x7fffu + ((u >> 16) & 1u);  // round-to-nearest-even
    return (uint16_t)(u >> 16);
}
// packed f32x2 -> bf16x2 (RNE), one instruction (HW-verified r9: %1 -> low 16, %2 -> high)
static __device__ __forceinline__ uint32_t cvt_pk_bf16(float lo, float hi) {
    uint32_t r;
    asm("v_cvt_pk_bf16_f32 %0, %1, %2" : "=v"(r) : "v"(lo), "v"(hi));
    return r;
}
// packed f32x2 -> f16x2 (RTZ), one instruction; <=1 ulp fp16 vs RNE.
// builtin returns __fp16 ext_vector(2) — take as auto, memcpy the bits (r8 fix).
static __device__ __forceinline__ uint32_t pkh(float lo, float hi) {
    auto h = __builtin_amdgcn_cvt_pkrtz(lo, hi);
    uint32_t u;
    __builtin_memcpy(&u, &h, 4);
    return u;
}
// D = 2^S0 (ISA §3 v_exp_f32); pure VALU, register-dep interlocked in HW
static __device__ __forceinline__ float exp2v(float x) {
    float r;
    asm("v_exp_f32 %0, %1" : "=v"(r) : "v"(x));
    return r;
}

// async global->LDS, 16B per lane (dest = wave-uniform base + lane*16 — our chunk layout).
static __device__ __forceinline__ void g2lds16(const void* g, void* l) {
    __builtin_amdgcn_global_load_lds((__attribute__((address_space(1))) void*)g,
                                     (__attribute__((address_space(3))) void*)l, 16, 0, 0);
}

#define LOG2E 1.44269504088896340f

// ---------- weights fp32->fp16 (+ zero the L accumulator), one launch ----------
// Wm: ic-columns perm64'd (chain-3, HW-verified r5).
// w_theta: pre-scaled by log2e (scores epilogue uses raw v_exp_f32; HW-verified r9).
__global__ void cvt_weights(const float* __restrict__ wphi, const float* __restrict__ wtheta,
                            const float* __restrict__ wg, const float* __restrict__ wmask,
                            uint16_t* __restrict__ W3, uint16_t* __restrict__ Wm, float* __restrict__ L) {
    int seg = blockIdx.y;
    int i = blockIdx.x * 256 + threadIdx.x;
    if (seg == 4) {
        if (i < 16384) L[i] = 0.f;
        return;
    }
    int base = i * 4;  // grid.x=128 -> base < 131072 exactly
    if (seg == 3) {
        // stored cols base..base+3 = row*256 + blk + 4a + {0..3}  <-  natural cols blk + a + 16i
        int row = base >> 8, dc = base & 255;
        int blk = dc & 192, a = (dc >> 2) & 15;
        const float* s = wmask + row * 256 + blk + a;
        *(ushort4*)(Wm + base) = make_ushort4(f2h(s[0]), f2h(s[16]), f2h(s[32]), f2h(s[48]));
        return;
    }
    const float* src = seg == 0 ? wphi : seg == 1 ? wtheta : wg;
    float4 v = *(const float4*)(src + base);
    float sc = (seg == 1) ? LOG2E : 1.f;
    *(ushort4*)(W3 + seg * 131072 + base) =
        make_ushort4(f2h(v.x * sc), f2h(v.y * sc), f2h(v.z * sc), f2h(v.w * sc));
}

// ---------- transpose x: (b,512,4096) f32 -> Xt (b,4096,512) f16 ----------
// r11 rewrite: fully vectorized global sides (G13). Phase 1: float4 loads (4 pixels/lane,
// 256B per 16-lane row) -> pixel-major LDS tile (scalar 2B writes, ~4-way conflict = cheap).
// Phase 2: 4 contiguous LDS reads -> ushort4 global stores (8B/lane). Mem instrs per
// thread: 32 -> 8. Same f2h RNE on the same elements -> values bit-identical to r10.
__global__ __launch_bounds__(256) void transpose_x(const float* __restrict__ x, uint16_t* __restrict__ xt) {
    __shared__ uint16_t tile[64][66];  // [pixel][channel], +2 pad
    int b = blockIdx.z, p0 = blockIdx.x * 64, c0 = blockIdx.y * 64;
    int i = threadIdx.x & 15, t1 = threadIdx.x >> 4;  // i: 4-pixel group, t1: 0..15
    const float* xb = x + ((long)b * 512 + c0) * 4096 + p0;
#pragma unroll
    for (int r = 0; r < 4; ++r) {
        int cc = t1 + r * 16;  // channel 0..63
        float4 v = *(const float4*)(xb + (long)cc * 4096 + 4 * i);
        tile[4 * i + 0][cc] = f2h(v.x);
        tile[4 * i + 1][cc] = f2h(v.y);
        tile[4 * i + 2][cc] = f2h(v.z);
        tile[4 * i + 3][cc] = f2h(v.w);
    }
    __syncthreads();
    uint16_t* xtb = xt + ((long)b * 4096 + p0) * 512 + c0;
#pragma unroll
    for (int r = 0; r < 4; ++r) {
        int pp = t1 + r * 16;  // pixel 0..63
        ushort4 u = make_ushort4(tile[pp][4 * i], tile[pp][4 * i + 1], tile[pp][4 * i + 2], tile[pp][4 * i + 3]);
        *(ushort4*)&xtb[(long)pp * 512 + 4 * i] = u;
    }
}

// ---------- scale+normalize g: Gc (fp16) -> Gc (bf16), element f *= 1/L[f & 2047] ----------
// Operates on STORED labels (chain-2): producers wrote Gc cols and L at the same relabel.
__global__ void scale_g(uint16_t* __restrict__ gc, const float* __restrict__ L) {
    long t = (long)blockIdx.x * 256 + threadIdx.x;  // 1,048,576 threads, 8 elems each
    long base = t * 8;
    int j0 = (int)(base & 2047);
    int b = (int)(base >> 20);  // 256*4096 elems per batch
    const float* Lp = L + (long)b * 2048 + j0;
    float4 l0 = *(const float4*)Lp;
    float4 l1 = *(const float4*)(Lp + 4);
    float rr[8] = {1.f / l0.x, 1.f / l0.y, 1.f / l0.z, 1.f / l0.w, 1.f / l1.x, 1.f / l1.y, 1.f / l1.z, 1.f / l1.w};
    uint4 v = *(uint4*)(gc + base);
    uint32_t* pv = (uint32_t*)&v;
    uint32_t o[4];
#pragma unroll
    for (int e = 0; e < 4; ++e) {
        float a = h2f((uint16_t)(pv[e] & 0xffffu)) * rr[2 * e];
        float c = h2f((uint16_t)(pv[e] >> 16)) * rr[2 * e + 1];
        o[e] = (uint32_t)f2bf(a) | ((uint32_t)f2bf(c) << 16);
    }
    *(uint4*)(gc + base) = *(uint4*)o;
}

// ---------- NT GEMM: C[m][n] = sum_k A[m][k]*B[n][k] ----------
// 128x128 tile, BK=64 staged as TWO stacked [128][32] LDS panels; nK = K/64.
// 4 waves each 64x64 (4x4 of 16x16x32 MFMA, 2 k-steps per iter).
// KHALF: for k>=256 both A and B row bases shift by 2048 rows, k -= 256 (channel-view split).
//
// Label relabels (perm64(l)=(l&15)*4+(l>>4) within 64-blocks):
//  chain-1 (HW-verified r10): C2 channel cols perm64'd; both scores operands read C2
//  linearly at 64-block-aligned bases -> k-sum label-invariant.
//  chain-2 (HW-verified r4): attention j-label shared by {P cols, L index, Gc pixel cols}.
//  chain-3 (HW-verified r5): Y2 de-interleaved+perm64'd via BMODE=3, matching perm'd Wm.
//
// XSWZ (HW-verified r7: scores FETCH 73.8->28.4 MB): 1D grid, wgid&7 = batch -> one batch
// per XCD (C2 4MB = L2/XCD); rest>>=3 decoded bx-fastest. gxs = log2(grid-x count).
//
// EPI: 0 = fp16 C, pkrtz-packed ushort4 over nt at perm64'd cols (PV -> Y2);
//      1 = fp32 C[m][n] + residual (final output, natural, scatter);
//      3 = mixed conv epilogue: n0<512 -> C2 packed ushort4 at perm64'd cols (chain-1);
//          n0>=512 -> transposed Gc[n-512][m], PIXEL cols perm64'd, pkrtz-packed over mt;
//      4 = bf16 P[m][n'] = 2^acc via v_exp_f32 + v_cvt_pk_bf16_f32, packed uint2 at
//          perm64'd cols; column sums shfl-transposed -> ONE lane-contiguous atomic/wave.
// SWAP: m0 from by, n0 from bx (consecutive blocks share the A-tile)
// BMODE: 0 = plain row*ldb async staging;
//        2 = mask B from de-interleaved Y2: row p -> (p&2047)*ldb + 256*(p>>11) (async);
//        3 = PV B de-interleave: logical col n reads Gc flat (n&255)*4096 + (n>>8)*2048 + k.
// DT: 0 = fp16 MFMA, 1 = bf16 MFMA (fragment/CD layouts are dtype-independent)
template <bool KHALF, int EPI, bool SWAP, int BMODE, int DT, bool XSWZ>
__global__ __launch_bounds__(256) void gemm_nt(const uint16_t* __restrict__ A, const uint16_t* __restrict__ B,
                                               void* __restrict__ Cout, const float* __restrict__ resid,
                                               int lda, int ldb, int ldc, int nK,
                                               long aBatch, long bBatch, long cBatch,
                                               void* __restrict__ Cout2, int ldc2, long c2Batch,
                                               float* __restrict__ Lsum, int gxs) {
    __shared__ uint16_t Al[2 * 128 * 32];
    __shared__ uint16_t Bl[2 * 128 * 32];
    int bx, by, b;
    if (XSWZ) {
        int wg = blockIdx.x;
        b = wg & 7;
        int rest = wg >> 3;
        bx = rest & ((1 << gxs) - 1);
        by = rest >> gxs;
    } else {
        bx = blockIdx.x; by = blockIdx.y; b = blockIdx.z;
    }
    const uint16_t* Ab = A + (long)b * aBatch;
    const uint16_t* Bb = B + (long)b * bBatch;
    const int m0 = (SWAP ? by : bx) * 128;
    const int n0 = (SWAP ? bx : by) * 128;
    const int tid = threadIdx.x;
    const int lane = tid & 63, wave = tid >> 6;
    const int ln = lane & 15, q = lane >> 4;
    const int wm = (wave & 1) * 64, wn = (wave >> 1) * 64;

    // softmax shift folded into the accumulator: acc holds S*log2e - 12*log2e (theta
    // pre-scaled by log2e at cvt time), so P = 2^acc directly.
    const float ainit = (EPI == 4) ? (-12.f * LOG2E) : 0.f;
    floatx4 acc[4][4];
#pragma unroll
    for (int i = 0; i < 4; ++i)
#pragma unroll
        for (int j = 0; j < 4; ++j) acc[i][j] = (floatx4){ainit, ainit, ainit, ainit};

    for (int kt = 0; kt < nK; ++kt) {
        int k0 = kt * 64;
#pragma unroll
        for (int half = 0; half < 2; ++half) {
            int kh = k0 + half * 32;
            int keff = kh;
            long roff = 0;
            if (KHALF && kh >= 256) { keff = kh - 256; roff = 2048; }
            uint16_t* AlH = &Al[half * 4096];
            uint16_t* BlH = &Bl[half * 4096];
#pragma unroll
            for (int s = 0; s < 2; ++s) {
                int c = tid + s * 256;  // 512 chunks of 16B per operand-panel
                int row = c >> 2, kq = (c & 3) * 8;
                g2lds16(Ab + ((long)(m0 + row) + roff) * lda + keff + kq, &AlH[c * 8]);
                if (BMODE == 0) {
                    g2lds16(Bb + ((long)(n0 + row) + roff) * ldb + keff + kq, &BlH[c * 8]);
                } else if (BMODE == 2) {
                    // mask B from de-interleaved Y2: pixel p -> stored row p&2047, +256 col
                    // offset for the upper pixel-half
                    int pg = n0 + row;
                    g2lds16(Bb + (long)(pg & 2047) * ldb + ((pg >> 11) << 8) + keff + kq, &BlH[c * 8]);
                } else {
                    // BMODE==3: logical col n -> Gc flat (n&255)*4096 + (n>>8)*2048 + k
                    int pr = n0 + row;
                    g2lds16(Bb + (long)(pr & 255) * 4096 + ((pr >> 8) << 11) + keff + kq, &BlH[c * 8]);
                }
            }
        }
        __syncthreads();
#pragma unroll
        for (int half = 0; half < 2; ++half) {
            const uint16_t* AlH = &Al[half * 4096];
            const uint16_t* BlH = &Bl[half * 4096];
            short8 af[4], bfr[4];
#pragma unroll
            for (int mt = 0; mt < 4; ++mt) af[mt] = *(const short8*)&AlH[(wm + mt * 16 + ln) * 32 + q * 8];
#pragma unroll
            for (int nt = 0; nt < 4; ++nt) bfr[nt] = *(const short8*)&BlH[(wn + nt * 16 + ln) * 32 + q * 8];
#pragma unroll
            for (int mt = 0; mt < 4; ++mt)
#pragma unroll
                for (int nt = 0; nt < 4; ++nt) {
                    if constexpr (DT == 0) {
                        half8 ah, bh;
                        __builtin_memcpy(&ah, &af[mt], 16);
                        __builtin_memcpy(&bh, &bfr[nt], 16);
                        acc[mt][nt] = __builtin_amdgcn_mfma_f32_16x16x32_f16(ah, bh, acc[mt][nt], 0, 0, 0);
                    } else {
                        acc[mt][nt] = __builtin_amdgcn_mfma_f32_16x16x32_bf16(af[mt], bfr[nt], acc[mt][nt], 0, 0, 0);
                    }
                }
        }
        __syncthreads();
    }

    // C/D layout (verified m89): col = lane&15, row = (lane>>4)*4 + reg
    // perm64 store identity: original col l = nt*16+ln -> stored col ln*4+nt (contig over nt)
    if (EPI == 0) {
        // PV -> Y2: pkrtz-packed ushort4 at perm64'd cols (chain-3)
        uint16_t* C = (uint16_t*)Cout + (long)b * cBatch;
        const int cb = n0 + wn + (ln << 2);
#pragma unroll
        for (int mt = 0; mt < 4; ++mt)
#pragma unroll
            for (int r = 0; r < 4; ++r) {
                int gm = m0 + wm + mt * 16 + q * 4 + r;
                uint2 u;
                u.x = pkh(acc[mt][0][r], acc[mt][1][r]);
                u.y = pkh(acc[mt][2][r], acc[mt][3][r]);
                *(uint2*)&C[(long)gm * ldc + cb] = u;
            }
    } else if (EPI == 3 && n0 < 512) {
        // C2: packed ushort4 at perm64'd channel cols (chain-1); f2h RNE keeps values
        // bit-identical to the scatter path — only the store addresses permute.
        uint16_t* C = (uint16_t*)Cout + (long)b * cBatch;
        const int cb = n0 + wn + (ln << 2);
#pragma unroll
        for (int mt = 0; mt < 4; ++mt)
#pragma unroll
            for (int r = 0; r < 4; ++r) {
                int gm = m0 + wm + mt * 16 + q * 4 + r;
                ushort4 u = make_ushort4(f2h(acc[mt][0][r]), f2h(acc[mt][1][r]),
                                         f2h(acc[mt][2][r]), f2h(acc[mt][3][r]));
                *(ushort4*)&C[(long)gm * ldc + cb] = u;
            }
    } else if (EPI == 4) {
        // P = 2^acc stored bf16 via v_exp_f32 + v_cvt_pk_bf16_f32, packed uint2 at
        // perm64'd cols; L accumulated from the exact fp32 values at the stored labels.
        uint16_t* C = (uint16_t*)Cout + (long)b * cBatch;
        const int cb = n0 + wn + (ln << 2);
        float cs[4] = {0.f, 0.f, 0.f, 0.f};
#pragma unroll
        for (int mt = 0; mt < 4; ++mt)
#pragma unroll
            for (int r = 0; r < 4; ++r) {
                int gm = m0 + wm + mt * 16 + q * 4 + r;
                float e0 = exp2v(acc[mt][0][r]);
                float e1 = exp2v(acc[mt][1][r]);
                float e2 = exp2v(acc[mt][2][r]);
                float e3 = exp2v(acc[mt][3][r]);
                cs[0] += e0; cs[1] += e1; cs[2] += e2; cs[3] += e3;
                uint2 wv;
                wv.x = cvt_pk_bf16(e0, e1);
                wv.y = cvt_pk_bf16(e2, e3);
                *(uint2*)&C[(long)gm * ldc + cb] = wv;
            }
        // q-fold: every lane then holds the full 64-row column sums for stored cols ln*4+nt
        cs[0] += __shfl_xor(cs[0], 16); cs[0] += __shfl_xor(cs[0], 32);
        cs[1] += __shfl_xor(cs[1], 16); cs[1] += __shfl_xor(cs[1], 32);
        cs[2] += __shfl_xor(cs[2], 16); cs[2] += __shfl_xor(cs[2], 32);
        cs[3] += __shfl_xor(cs[3], 16); cs[3] += __shfl_xor(cs[3], 32);
        // shfl-transpose: lane l takes cs[l&3] from lane (l>>2) -> ONE lane-contiguous
        // atomic per wave (64 consecutive floats, 4 cachelines; r4-verified)
        {
            int srcl = lane >> 2;
            float t0 = __shfl(cs[0], srcl);
            float t1 = __shfl(cs[1], srcl);
            float t2 = __shfl(cs[2], srcl);
            float t3 = __shfl(cs[3], srcl);
            int sel = lane & 3;
            float val = sel == 0 ? t0 : sel == 1 ? t1 : sel == 2 ? t2 : t3;
            atomicAdd(&Lsum[(long)b * 2048 + n0 + wn + lane], val);
        }
    } else if (EPI == 1) {
        float* C = (float*)Cout + (long)b * cBatch;
        const float* X = resid + (long)b * cBatch;
#pragma unroll
        for (int mt = 0; mt < 4; ++mt)
#pragma unroll
            for (int r = 0; r < 4; ++r) {
                int gm = m0 + wm + mt * 16 + q * 4 + r;
#pragma unroll
                for (int nt = 0; nt < 4; ++nt) {
                    int gn = n0 + wn + nt * 16 + ln;
                    long idx = (long)gm * ldc + gn;
                    C[idx] = acc[mt][nt][r] + X[idx];
                }
            }
    } else {
        // transposed epilogue into Cout2: row = gn - 512; pixel cols perm64'd (chain-2):
        // original pixel l = mt*16 + q*4 + r -> stored col q*16 + r*4 + mt (contig over mt)
        uint16_t* C = (uint16_t*)Cout2 + (long)b * c2Batch;
        const int cb = m0 + wm + q * 16;
#pragma unroll
        for (int nt = 0; nt < 4; ++nt) {
            int gn2 = n0 - 512 + wn + nt * 16 + ln;
            uint16_t* rowp = C + (long)gn2 * ldc2 + cb;
#pragma unroll
            for (int r = 0; r < 4; ++r) {
                uint2 u;
                u.x = pkh(acc[0][nt][r], acc[1][nt][r]);
                u.y = pkh(acc[2][nt][r], acc[3][nt][r]);
                *(uint2*)&rowp[r * 4] = u;
            }
        }
    }
}

// ---------- launch ----------
// ws layout:
//   W3 @ 0 (768x512 f16: phi|theta(x log2e)|g) ; Wm @ 786432 (512x256 f16, perm64 cols)
//   L  @ 1048576 (8x2048 f32)
//   A_region @ 1179648  (64 MB): Xt (32 MB) -> P (64 MB bf16)
//   B_region @ 68288512 (48 MB): C2 (32 MB) -> Y2 (16 MB) @ +0 ; Gc (16 MB) @ +32MB
// chain-1 (HW-verified r10): C2 channel cols perm64'd.
// chain-2 (HW-verified r4): j-label perm64 shared by {P cols, L index, Gc pixel cols}.
// chain-3 (HW-verified r5): PV BMODE=3 + EPI=0 perm64 store lands Y2 de-interleaved+
//   perm64'd, matching perm'd Wm + mask BMODE=2 async staging.
// XSWZ (HW-verified r7): 1D grids, wgid&7 = batch -> one batch per XCD.
extern "C" void kernel_launch(void* const* d_in, const int* in_sizes, int n_in, void* d_out, int out_size, void* d_ws,
                              size_t ws_size, hipStream_t stream) {
    const float* x = (const float*)d_in[0];
    const float* wphi = (const float*)d_in[1];
    const float* wtheta = (const float*)d_in[2];
    const float* wg = (const float*)d_in[3];
    const float* wmask = (const float*)d_in[4];
    float* out = (float*)d_out;
    char* ws = (char*)d_ws;

    uint16_t* W3 = (uint16_t*)(ws + 0);
    uint16_t* Wm = (uint16_t*)(ws + 786432);
    float* L = (float*)(ws + 1048576);
    char* A_region = ws + 1179648;
    char* B_region = ws + 68288512;
    uint16_t* Xt = (uint16_t*)A_region;
    uint16_t* P = (uint16_t*)A_region;
    uint16_t* C2 = (uint16_t*)B_region;
    uint16_t* Y2 = (uint16_t*)B_region;
    uint16_t* Gc = (uint16_t*)(B_region + 33554432);

    // weights -> fp16 (Wm perm64'd, theta x log2e), L zeroed (one launch)
    cvt_weights<<<dim3(128, 5), 256, 0, stream>>>(wphi, wtheta, wg, wmask, W3, Wm, L);

    // x -> Xt (pixel-major fp16), vectorized (r11)
    transpose_x<<<dim3(64, 8, 8), 256, 0, stream>>>(x, Xt);

    // fused 3-conv: 1536 = 8 batches x (32 m x 6 n), gxs=5. n0<512 -> C2 packed at
    // perm64'd channel cols (chain-1), n0>=512 -> Gc transposed, perm64'd pixel cols
    // (chain-2).
    gemm_nt<false, 3, false, 0, 0, true><<<dim3(1536), 256, 0, stream>>>(
        Xt, W3, C2, nullptr, 512, 512, 512, 8, 4096L * 512, 0, 4096L * 512, Gc, 4096, 256L * 4096, nullptr, 5);

    // scores (k-half row shift): 2048 = 8 x (16 m x 16 n), gxs=4. P[i][j'] = bf16(2^acc)
    // packed, L[j'] += 2^acc via per-wave lane-contiguous atomics; overwrites Xt (dead).
    gemm_nt<true, 4, false, 0, 0, true><<<dim3(2048), 256, 0, stream>>>(
        C2 + 256, C2, P, nullptr, 512, 512, 2048, 8, 4096L * 512, 4096L * 512, 2048L * 2048, nullptr, 0, 0, L, 4);

    // Gc[c][j'] *= 1/L[j'], fp16 -> bf16 in place (stored labels on both sides)
    scale_g<<<4096, 256, 0, stream>>>(Gc, L);

    // PV (bf16, all-async): 512 = 8 x (4 n x 16 m), gxs=2 with SWAP. BMODE=3 de-interleave
    // staging lands Y2 de-interleaved+perm64'd; EPI=0 pkrtz-packs. Y2 reuses C2 (dead).
    gemm_nt<false, 0, true, 3, 1, true><<<dim3(512), 256, 0, stream>>>(
        P, Gc, Y2, nullptr, 2048, 2048, 512, 32, 2048L * 2048, 1048576L, 2048L * 512, nullptr, 0, 0, nullptr, 2);

    // mask conv + residual: 1024 = 8 x (4 m x 32 n), gxs=2. B staged ASYNC from
    // de-interleaved Y2 (BMODE=2), Wm perm64'd.
    gemm_nt<false, 1, false, 2, 0, true><<<dim3(1024), 256, 0, stream>>>(
        Wm, Y2, out, x, 256, 512, 4096, 4, 0, 1048576L, 512L * 4096, nullptr, 0, 0, nullptr, 2);
}